// Round 1
// baseline (112.805 us; speedup 1.0000x reference)
//
#include <hip/hip_runtime.h>
#include <hip/hip_bf16.h>

typedef __attribute__((ext_vector_type(8))) short short8b;
typedef __attribute__((ext_vector_type(4))) float float4v;

// ---------------------------------------------------------------------------
// K0: f32 -> bf16 cast (vectorized: float4 in, 4x bf16 out)
// ---------------------------------------------------------------------------
__global__ void cast_f32_to_bf16(const float* __restrict__ src,
                                 __hip_bfloat16* __restrict__ dst, int n4) {
    int i = blockIdx.x * blockDim.x + threadIdx.x;
    if (i >= n4) return;
    float4 v = reinterpret_cast<const float4*>(src)[i];
    union { ushort4 u; __hip_bfloat16 h[4]; } o;
    o.h[0] = __float2bfloat16(v.x);
    o.h[1] = __float2bfloat16(v.y);
    o.h[2] = __float2bfloat16(v.z);
    o.h[3] = __float2bfloat16(v.w);
    reinterpret_cast<ushort4*>(dst)[i] = o.u;
}

// ---------------------------------------------------------------------------
// K1: projection GEMM. C(4096 x 1280) = X(4096 x 256) @ W^T, W row-major
// (1280 x 256: rows 0-767 = in_proj_weight, 768-1279 = in_proj_weight_self).
// Epilogue adds bias, applies q-scaling, scatters into per-head tensors:
//   Qs,K,Qf,Kf : [bh][2048][32] bf16     V -> Vt : [bh][32][2048] bf16
// ---------------------------------------------------------------------------
__global__ __launch_bounds__(256) void proj_gemm(
    const __hip_bfloat16* __restrict__ X, const __hip_bfloat16* __restrict__ W,
    const float* __restrict__ bias, const float* __restrict__ bias_s,
    __hip_bfloat16* __restrict__ Qs, __hip_bfloat16* __restrict__ Kg,
    __hip_bfloat16* __restrict__ Vt, __hip_bfloat16* __restrict__ Qf,
    __hip_bfloat16* __restrict__ Kf) {
    __shared__ __hip_bfloat16 At[128][40];   // padded: 80B rows -> b128 reads conflict-free
    __shared__ __hip_bfloat16 Bt[128][40];
    const int tid = threadIdx.x;
    const int lane = tid & 63, w = tid >> 6;
    const int ln = lane & 15, kg = lane >> 4;
    const int wr = w >> 1, wc = w & 1;
    const int rowBase = blockIdx.y * 128;
    const int colBase = blockIdx.x * 128;
    float4v acc[4][4] = {};

    for (int kt = 0; kt < 8; ++kt) {
        int cid = tid;
#pragma unroll
        for (int p = 0; p < 2; ++p, cid += 256) {
            int row = cid >> 2, c = cid & 3;
            *(short8b*)&At[row][c * 8] =
                *(const short8b*)&X[(rowBase + row) * 256 + kt * 32 + c * 8];
            *(short8b*)&Bt[row][c * 8] =
                *(const short8b*)&W[(colBase + row) * 256 + kt * 32 + c * 8];
        }
        __syncthreads();
        short8b a[4], b[4];
#pragma unroll
        for (int mi = 0; mi < 4; ++mi) a[mi] = *(const short8b*)&At[wr * 64 + mi * 16 + ln][kg * 8];
#pragma unroll
        for (int nj = 0; nj < 4; ++nj) b[nj] = *(const short8b*)&Bt[wc * 64 + nj * 16 + ln][kg * 8];
#pragma unroll
        for (int mi = 0; mi < 4; ++mi)
#pragma unroll
            for (int nj = 0; nj < 4; ++nj)
                acc[mi][nj] = __builtin_amdgcn_mfma_f32_16x16x32_bf16(a[mi], b[nj], acc[mi][nj], 0, 0, 0);
        __syncthreads();
    }

    const float scaling = 0.17677669529663687f;  // 32^-0.5
#pragma unroll
    for (int mi = 0; mi < 4; ++mi) {
#pragma unroll
        for (int nj = 0; nj < 4; ++nj) {
            int j = colBase + wc * 64 + nj * 16 + ln;
            float bj = (j < 768) ? bias[j] : bias_s[j - 768];
#pragma unroll
            for (int r = 0; r < 4; ++r) {
                int row = rowBase + wr * 64 + mi * 16 + kg * 4 + r;
                float val = acc[mi][nj][r] + bj;
                int l = row >> 1, n = row & 1;
                if (j < 256) {
                    int h = j >> 5, d = j & 31;
                    Qs[(((n << 3) + h) * 2048 + l) * 32 + d] = __float2bfloat16(val * scaling);
                } else if (j < 512) {
                    int e = j - 256, h = e >> 5, d = e & 31;
                    Kg[(((n << 3) + h) * 2048 + l) * 32 + d] = __float2bfloat16(val);
                } else if (j < 768) {
                    int e = j - 512, h = e >> 5, d = e & 31;
                    Vt[(((n << 3) + h) * 32 + d) * 2048 + l] = __float2bfloat16(val);
                } else if (j < 1024) {
                    int e = j - 768, h = e >> 5, d = e & 31;
                    Qf[(((n << 3) + h) * 2048 + l) * 32 + d] = __float2bfloat16(val * scaling);
                } else {
                    int e = j - 1024, h = e >> 5, d = e & 31;
                    Kf[(((n << 3) + h) * 2048 + l) * 32 + d] = __float2bfloat16(val);
                }
            }
        }
    }
}

// ---------------------------------------------------------------------------
// K2: agent-aware flash attention.
// grid (32 qtiles, 16 bh); block 256 = 4 waves; wave owns 16 q-rows.
// Per 64-key S-tile: stage K, K_self (64x32) and V^T (32x64) in padded LDS,
// dual QK^T MFMA, blend by (qid==kid), online softmax, P->LDS->A-frag, PV MFMA.
// ---------------------------------------------------------------------------
__global__ __launch_bounds__(256) void agent_attn(
    const __hip_bfloat16* __restrict__ Qs, const __hip_bfloat16* __restrict__ Kg,
    const __hip_bfloat16* __restrict__ Vt, const __hip_bfloat16* __restrict__ Qf,
    const __hip_bfloat16* __restrict__ Kf, const int* __restrict__ qid_g,
    const int* __restrict__ kid_g, __hip_bfloat16* __restrict__ Ab) {
    __shared__ __hip_bfloat16 Kt[64][40];
    __shared__ __hip_bfloat16 Ks[64][40];
    __shared__ __hip_bfloat16 Vts[32][72];
    __shared__ __hip_bfloat16 Pw[4][16][72];
    __shared__ int sids[64];
    const int tid = threadIdx.x;
    const int lane = tid & 63, w = tid >> 6;
    const int ln = lane & 15, kg = lane >> 4;
    const int bh = blockIdx.y;
    const int n = bh >> 3, h = bh & 7;
    const int q0 = blockIdx.x * 64 + w * 16;

    // Q fragments held in registers for the whole kernel (row = ln, k = kg*8..)
    short8b aQ  = *(const short8b*)&Qs[(bh * 2048 + q0 + ln) * 32 + kg * 8];
    short8b aQf = *(const short8b*)&Qf[(bh * 2048 + q0 + ln) * 32 + kg * 8];
    int qid[4];
#pragma unroll
    for (int r = 0; r < 4; ++r) qid[r] = qid_g[q0 + kg * 4 + r];

    float mrun[4], lsum[4];
    float4v O0 = {}, O1 = {};
#pragma unroll
    for (int r = 0; r < 4; ++r) { mrun[r] = -1e30f; lsum[r] = 0.f; }

    for (int st = 0; st < 32; ++st) {
        const int s0 = st * 64;
        {  // cooperative stage (256 threads)
            int row = tid >> 2, c = tid & 3;
            *(short8b*)&Kt[row][c * 8] = *(const short8b*)&Kg[(bh * 2048 + s0 + row) * 32 + c * 8];
            *(short8b*)&Ks[row][c * 8] = *(const short8b*)&Kf[(bh * 2048 + s0 + row) * 32 + c * 8];
            int d = tid >> 3, cv = tid & 7;
            *(short8b*)&Vts[d][cv * 8] = *(const short8b*)&Vt[(bh * 32 + d) * 2048 + s0 + cv * 8];
            if (tid < 64) sids[tid] = kid_g[s0 + tid];
        }
        __syncthreads();

        float sv[4][4];
#pragma unroll
        for (int sub = 0; sub < 4; ++sub) {
            short8b bK = *(const short8b*)&Kt[sub * 16 + ln][kg * 8];
            short8b bS = *(const short8b*)&Ks[sub * 16 + ln][kg * 8];
            float4v z = {};
            float4v ci = __builtin_amdgcn_mfma_f32_16x16x32_bf16(aQ, bK, z, 0, 0, 0);
            float4v cs = __builtin_amdgcn_mfma_f32_16x16x32_bf16(aQf, bS, z, 0, 0, 0);
            int sid = sids[sub * 16 + ln];
#pragma unroll
            for (int r = 0; r < 4; ++r) sv[sub][r] = (qid[r] == sid) ? cs[r] : ci[r];
        }

        // online softmax (row r lives in lanes {kg*16 .. kg*16+15}, reg r)
        float p[4][4];
#pragma unroll
        for (int r = 0; r < 4; ++r) {
            float tm = fmaxf(fmaxf(sv[0][r], sv[1][r]), fmaxf(sv[2][r], sv[3][r]));
            tm = fmaxf(tm, __shfl_xor(tm, 1));
            tm = fmaxf(tm, __shfl_xor(tm, 2));
            tm = fmaxf(tm, __shfl_xor(tm, 4));
            tm = fmaxf(tm, __shfl_xor(tm, 8));
            float mn = fmaxf(mrun[r], tm);
            float sc = __expf(mrun[r] - mn);
            mrun[r] = mn;
            float ps = 0.f;
#pragma unroll
            for (int sub = 0; sub < 4; ++sub) {
                float e = __expf(sv[sub][r] - mn);
                p[sub][r] = e;
                ps += e;
            }
            ps += __shfl_xor(ps, 1);
            ps += __shfl_xor(ps, 2);
            ps += __shfl_xor(ps, 4);
            ps += __shfl_xor(ps, 8);
            lsum[r] = lsum[r] * sc + ps;
            O0[r] *= sc;
            O1[r] *= sc;
        }

        // P (16 x 64) -> per-wave LDS, then read back as A-fragments
#pragma unroll
        for (int sub = 0; sub < 4; ++sub)
#pragma unroll
            for (int r = 0; r < 4; ++r)
                Pw[w][kg * 4 + r][sub * 16 + ln] = __float2bfloat16(p[sub][r]);

#pragma unroll
        for (int kk = 0; kk < 2; ++kk) {
            short8b aP  = *(const short8b*)&Pw[w][ln][kk * 32 + kg * 8];
            short8b bV0 = *(const short8b*)&Vts[ln][kk * 32 + kg * 8];
            short8b bV1 = *(const short8b*)&Vts[16 + ln][kk * 32 + kg * 8];
            O0 = __builtin_amdgcn_mfma_f32_16x16x32_bf16(aP, bV0, O0, 0, 0, 0);
            O1 = __builtin_amdgcn_mfma_f32_16x16x32_bf16(aP, bV1, O1, 0, 0, 0);
        }
        __syncthreads();
    }

#pragma unroll
    for (int r = 0; r < 4; ++r) {
        float inv = 1.0f / lsum[r];
        int l = q0 + kg * 4 + r;
        int rowo = (l * 2 + n) * 256 + h * 32;
        Ab[rowo + ln]      = __float2bfloat16(O0[r] * inv);
        Ab[rowo + 16 + ln] = __float2bfloat16(O1[r] * inv);
    }
}

// ---------------------------------------------------------------------------
// K3: out projection. out(4096 x 256, f32) = Ab(4096 x 256) @ Wob^T + bias
// ---------------------------------------------------------------------------
__global__ __launch_bounds__(256) void out_gemm(
    const __hip_bfloat16* __restrict__ A, const __hip_bfloat16* __restrict__ W,
    const float* __restrict__ bias, float* __restrict__ out) {
    __shared__ __hip_bfloat16 At[128][40];
    __shared__ __hip_bfloat16 Bt[128][40];
    const int tid = threadIdx.x;
    const int lane = tid & 63, w = tid >> 6;
    const int ln = lane & 15, kg = lane >> 4;
    const int wr = w >> 1, wc = w & 1;
    const int rowBase = blockIdx.y * 128;
    const int colBase = blockIdx.x * 128;
    float4v acc[4][4] = {};

    for (int kt = 0; kt < 8; ++kt) {
        int cid = tid;
#pragma unroll
        for (int p = 0; p < 2; ++p, cid += 256) {
            int row = cid >> 2, c = cid & 3;
            *(short8b*)&At[row][c * 8] =
                *(const short8b*)&A[(rowBase + row) * 256 + kt * 32 + c * 8];
            *(short8b*)&Bt[row][c * 8] =
                *(const short8b*)&W[(colBase + row) * 256 + kt * 32 + c * 8];
        }
        __syncthreads();
        short8b a[4], b[4];
#pragma unroll
        for (int mi = 0; mi < 4; ++mi) a[mi] = *(const short8b*)&At[wr * 64 + mi * 16 + ln][kg * 8];
#pragma unroll
        for (int nj = 0; nj < 4; ++nj) b[nj] = *(const short8b*)&Bt[wc * 64 + nj * 16 + ln][kg * 8];
#pragma unroll
        for (int mi = 0; mi < 4; ++mi)
#pragma unroll
            for (int nj = 0; nj < 4; ++nj)
                acc[mi][nj] = __builtin_amdgcn_mfma_f32_16x16x32_bf16(a[mi], b[nj], acc[mi][nj], 0, 0, 0);
        __syncthreads();
    }

#pragma unroll
    for (int mi = 0; mi < 4; ++mi) {
#pragma unroll
        for (int nj = 0; nj < 4; ++nj) {
            int j = colBase + wc * 64 + nj * 16 + ln;
            float bj = bias[j];
#pragma unroll
            for (int r = 0; r < 4; ++r) {
                int row = rowBase + wr * 64 + mi * 16 + kg * 4 + r;
                out[row * 256 + j] = acc[mi][nj][r] + bj;
            }
        }
    }
}

// ---------------------------------------------------------------------------
extern "C" void kernel_launch(void* const* d_in, const int* in_sizes, int n_in,
                              void* d_out, int out_size, void* d_ws, size_t ws_size,
                              hipStream_t stream) {
    const float* query = (const float*)d_in[0];   // (2048, 2, 256)
    const float* W_in  = (const float*)d_in[1];   // (768, 256)
    const float* b_in  = (const float*)d_in[2];   // (768,)
    const float* W_s   = (const float*)d_in[3];   // (512, 256)
    const float* b_s   = (const float*)d_in[4];   // (512,)
    const float* W_o   = (const float*)d_in[5];   // (256, 256)
    const float* b_o   = (const float*)d_in[6];   // (256,)
    const int*   qids  = (const int*)d_in[7];     // (2048,)
    const int*   kids  = (const int*)d_in[8];     // (2048,)
    float* out = (float*)d_out;                   // (2048, 2, 256) f32

    __hip_bfloat16* Xb  = (__hip_bfloat16*)d_ws;       // 4096 x 256
    __hip_bfloat16* Wb  = Xb + 4096 * 256;             // 1280 x 256
    __hip_bfloat16* Wob = Wb + 1280 * 256;             // 256 x 256
    __hip_bfloat16* Qs  = Wob + 256 * 256;             // [16][2048][32]
    __hip_bfloat16* Kg  = Qs + 16 * 2048 * 32;
    __hip_bfloat16* Vt  = Kg + 16 * 2048 * 32;         // [16][32][2048]
    __hip_bfloat16* Qf  = Vt + 16 * 2048 * 32;
    __hip_bfloat16* Kf  = Qf + 16 * 2048 * 32;
    __hip_bfloat16* Ab  = Kf + 16 * 2048 * 32;         // 4096 x 256

    cast_f32_to_bf16<<<1024, 256, 0, stream>>>(query, Xb, 262144);
    cast_f32_to_bf16<<<192, 256, 0, stream>>>(W_in, Wb, 49152);
    cast_f32_to_bf16<<<128, 256, 0, stream>>>(W_s, Wb + 768 * 256, 32768);
    cast_f32_to_bf16<<<64, 256, 0, stream>>>(W_o, Wob, 16384);
    proj_gemm<<<dim3(10, 32), 256, 0, stream>>>(Xb, Wb, b_in, b_s, Qs, Kg, Vt, Qf, Kf);
    agent_attn<<<dim3(32, 16), 256, 0, stream>>>(Qs, Kg, Vt, Qf, Kf, qids, kids, Ab);
    out_gemm<<<dim3(2, 32), 256, 0, stream>>>(Ab, Wob, b_o, out);
}

// Round 2
// 102.771 us; speedup vs baseline: 1.0976x; 1.0976x over previous
//
#include <hip/hip_runtime.h>
#include <hip/hip_bf16.h>

typedef __attribute__((ext_vector_type(8))) short short8b;
typedef __attribute__((ext_vector_type(4))) float float4v;

// ---------------------------------------------------------------------------
// K0: fused f32 -> bf16 cast for query + all three weight matrices.
// Grid covers 360448 float4 groups: [query 262144 | W_in 49152 | W_s 32768 | W_o 16384]
// ---------------------------------------------------------------------------
__global__ __launch_bounds__(256) void cast_all(
    const float* __restrict__ q, const float* __restrict__ w1,
    const float* __restrict__ w2, const float* __restrict__ w3,
    __hip_bfloat16* __restrict__ Xb, __hip_bfloat16* __restrict__ Wb,
    __hip_bfloat16* __restrict__ Wob) {
  int i = blockIdx.x * blockDim.x + threadIdx.x;
  if (i >= 360448) return;
  const float* src; __hip_bfloat16* dst; int j;
  if (i < 262144)      { src = q;  dst = Xb;          j = i; }
  else if (i < 311296) { src = w1; dst = Wb;          j = i - 262144; }
  else if (i < 344064) { src = w2; dst = Wb + 196608; j = i - 311296; }
  else                 { src = w3; dst = Wob;         j = i - 344064; }
  float4 v = reinterpret_cast<const float4*>(src)[j];
  union { ushort4 u; __hip_bfloat16 h[4]; } o;
  o.h[0] = __float2bfloat16(v.x); o.h[1] = __float2bfloat16(v.y);
  o.h[2] = __float2bfloat16(v.z); o.h[3] = __float2bfloat16(v.w);
  reinterpret_cast<ushort4*>(dst)[j] = o.u;
}

// ---------------------------------------------------------------------------
// K1: projection GEMM. C(4096 x 1280) = X(4096 x 256) @ W^T, W row-major
// (rows 0-767 = in_proj_weight, 768-1279 = in_proj_weight_self).
// Epilogue adds bias, applies q-scaling, scatters into per-head tensors:
//   Qs,K,Qf,Kf : [bh][2048][32] bf16     V -> Vt : [bh][32][2048] bf16
// ---------------------------------------------------------------------------
__global__ __launch_bounds__(256) void proj_gemm(
    const __hip_bfloat16* __restrict__ X, const __hip_bfloat16* __restrict__ W,
    const float* __restrict__ bias, const float* __restrict__ bias_s,
    __hip_bfloat16* __restrict__ Qs, __hip_bfloat16* __restrict__ Kg,
    __hip_bfloat16* __restrict__ Vt, __hip_bfloat16* __restrict__ Qf,
    __hip_bfloat16* __restrict__ Kf) {
    __shared__ __hip_bfloat16 At[128][40];
    __shared__ __hip_bfloat16 Bt[128][40];
    const int tid = threadIdx.x;
    const int lane = tid & 63, w = tid >> 6;
    const int ln = lane & 15, kg = lane >> 4;
    const int wr = w >> 1, wc = w & 1;
    const int rowBase = blockIdx.y * 128;
    const int colBase = blockIdx.x * 128;
    float4v acc[4][4] = {};

    for (int kt = 0; kt < 8; ++kt) {
        int cid = tid;
#pragma unroll
        for (int p = 0; p < 2; ++p, cid += 256) {
            int row = cid >> 2, c = cid & 3;
            *(short8b*)&At[row][c * 8] =
                *(const short8b*)&X[(rowBase + row) * 256 + kt * 32 + c * 8];
            *(short8b*)&Bt[row][c * 8] =
                *(const short8b*)&W[(colBase + row) * 256 + kt * 32 + c * 8];
        }
        __syncthreads();
        short8b a[4], b[4];
#pragma unroll
        for (int mi = 0; mi < 4; ++mi) a[mi] = *(const short8b*)&At[wr * 64 + mi * 16 + ln][kg * 8];
#pragma unroll
        for (int nj = 0; nj < 4; ++nj) b[nj] = *(const short8b*)&Bt[wc * 64 + nj * 16 + ln][kg * 8];
#pragma unroll
        for (int mi = 0; mi < 4; ++mi)
#pragma unroll
            for (int nj = 0; nj < 4; ++nj)
                acc[mi][nj] = __builtin_amdgcn_mfma_f32_16x16x32_bf16(a[mi], b[nj], acc[mi][nj], 0, 0, 0);
        __syncthreads();
    }

    const float scaling = 0.17677669529663687f;  // 32^-0.5
#pragma unroll
    for (int mi = 0; mi < 4; ++mi) {
#pragma unroll
        for (int nj = 0; nj < 4; ++nj) {
            int j = colBase + wc * 64 + nj * 16 + ln;
            float bj = (j < 768) ? bias[j] : bias_s[j - 768];
#pragma unroll
            for (int r = 0; r < 4; ++r) {
                int row = rowBase + wr * 64 + mi * 16 + kg * 4 + r;
                float val = acc[mi][nj][r] + bj;
                int l = row >> 1, n = row & 1;
                if (j < 256) {
                    int h = j >> 5, d = j & 31;
                    Qs[(((n << 3) + h) * 2048 + l) * 32 + d] = __float2bfloat16(val * scaling);
                } else if (j < 512) {
                    int e = j - 256, h = e >> 5, d = e & 31;
                    Kg[(((n << 3) + h) * 2048 + l) * 32 + d] = __float2bfloat16(val);
                } else if (j < 768) {
                    int e = j - 512, h = e >> 5, d = e & 31;
                    Vt[(((n << 3) + h) * 32 + d) * 2048 + l] = __float2bfloat16(val);
                } else if (j < 1024) {
                    int e = j - 768, h = e >> 5, d = e & 31;
                    Qf[(((n << 3) + h) * 2048 + l) * 32 + d] = __float2bfloat16(val * scaling);
                } else {
                    int e = j - 1024, h = e >> 5, d = e & 31;
                    Kf[(((n << 3) + h) * 2048 + l) * 32 + d] = __float2bfloat16(val);
                }
            }
        }
    }
}

// ---------------------------------------------------------------------------
// K2: agent-aware flash attention, barrier-free, split-S.
// grid: 2048 1-D blocks of 128 threads (2 independent waves, 32 q-rows each).
// Block decode (XCD-aware, dispatch round-robins linear id over 8 XCDs):
//   xcd = flat&7 -> bh in {2*xcd, 2*xcd+1}; 32 q-groups x 4 S-splits per bh.
// No K/V LDS staging: fragments read straight from L2-resident per-head
// tensors. P goes through a tiny per-wave LDS buffer (no __syncthreads).
// Partials (O f32, m, l) written per split; merged by K2b.
// ---------------------------------------------------------------------------
__global__ __launch_bounds__(128) void agent_attn(
    const __hip_bfloat16* __restrict__ Qs, const __hip_bfloat16* __restrict__ Kg,
    const __hip_bfloat16* __restrict__ Vt, const __hip_bfloat16* __restrict__ Qf,
    const __hip_bfloat16* __restrict__ Kf, const int* __restrict__ qid_g,
    const int* __restrict__ kid_g, float* __restrict__ PO, float* __restrict__ PML) {
  __shared__ __hip_bfloat16 Pw[2][16][68];   // 68-short rows: conflict-light
  const int tid = threadIdx.x;
  const int lane = tid & 63, w = tid >> 6;
  const int ln = lane & 15, kg = lane >> 4;

  const int flat = blockIdx.x;
  const int slot = flat >> 3;
  const int bh = ((flat & 7) << 1) | (slot & 1);
  const int qs = slot >> 1;
  const int qg = qs & 31, split = qs >> 5;
  const int q0 = qg * 64 + w * 32;

  const __hip_bfloat16* Qb  = Qs + (size_t)bh * 2048 * 32;
  const __hip_bfloat16* Qfb = Qf + (size_t)bh * 2048 * 32;
  const __hip_bfloat16* Kb  = Kg + (size_t)bh * 2048 * 32;
  const __hip_bfloat16* Ksb = Kf + (size_t)bh * 2048 * 32;
  const __hip_bfloat16* Vb  = Vt + (size_t)bh * 32 * 2048;

  short8b aQ[2], aQf[2];
  int qidv[2][4];
#pragma unroll
  for (int qh = 0; qh < 2; ++qh) {
    aQ[qh]  = *(const short8b*)&Qb [(q0 + qh * 16 + ln) * 32 + kg * 8];
    aQf[qh] = *(const short8b*)&Qfb[(q0 + qh * 16 + ln) * 32 + kg * 8];
#pragma unroll
    for (int r = 0; r < 4; ++r) qidv[qh][r] = qid_g[q0 + qh * 16 + kg * 4 + r];
  }

  float mrun[2][4], lsum[2][4];
  float4v O[2][2];
#pragma unroll
  for (int qh = 0; qh < 2; ++qh) {
#pragma unroll
    for (int r = 0; r < 4; ++r) { mrun[qh][r] = -1e30f; lsum[qh][r] = 0.f; }
    O[qh][0] = (float4v){0.f, 0.f, 0.f, 0.f};
    O[qh][1] = (float4v){0.f, 0.f, 0.f, 0.f};
  }

#pragma unroll 2
  for (int st = split * 8; st < split * 8 + 8; ++st) {
    const int s0 = st * 64;
    short8b bK[4], bS[4]; int sid[4];
#pragma unroll
    for (int sub = 0; sub < 4; ++sub) {
      bK[sub] = *(const short8b*)&Kb [(s0 + sub * 16 + ln) * 32 + kg * 8];
      bS[sub] = *(const short8b*)&Ksb[(s0 + sub * 16 + ln) * 32 + kg * 8];
      sid[sub] = kid_g[s0 + sub * 16 + ln];
    }
    short8b bV[2][2];
#pragma unroll
    for (int kk = 0; kk < 2; ++kk)
#pragma unroll
      for (int dh = 0; dh < 2; ++dh)
        bV[kk][dh] = *(const short8b*)&Vb[(dh * 16 + ln) * 2048 + s0 + kk * 32 + kg * 8];

    float sv[2][4][4];
#pragma unroll
    for (int qh = 0; qh < 2; ++qh)
#pragma unroll
      for (int sub = 0; sub < 4; ++sub) {
        float4v z = {0.f, 0.f, 0.f, 0.f};
        float4v ci = __builtin_amdgcn_mfma_f32_16x16x32_bf16(aQ[qh],  bK[sub], z, 0, 0, 0);
        float4v cs = __builtin_amdgcn_mfma_f32_16x16x32_bf16(aQf[qh], bS[sub], z, 0, 0, 0);
#pragma unroll
        for (int r = 0; r < 4; ++r)
          sv[qh][sub][r] = (qidv[qh][r] == sid[sub]) ? cs[r] : ci[r];
      }

#pragma unroll
    for (int qh = 0; qh < 2; ++qh) {
      float p[4][4];
#pragma unroll
      for (int r = 0; r < 4; ++r) {
        float tm = fmaxf(fmaxf(sv[qh][0][r], sv[qh][1][r]),
                         fmaxf(sv[qh][2][r], sv[qh][3][r]));
        tm = fmaxf(tm, __shfl_xor(tm, 1));
        tm = fmaxf(tm, __shfl_xor(tm, 2));
        tm = fmaxf(tm, __shfl_xor(tm, 4));
        tm = fmaxf(tm, __shfl_xor(tm, 8));
        float mn = fmaxf(mrun[qh][r], tm);
        float sc = __expf(mrun[qh][r] - mn);
        mrun[qh][r] = mn;
        float ps = 0.f;
#pragma unroll
        for (int sub = 0; sub < 4; ++sub) {
          float e = __expf(sv[qh][sub][r] - mn);
          p[sub][r] = e; ps += e;
        }
        ps += __shfl_xor(ps, 1);
        ps += __shfl_xor(ps, 2);
        ps += __shfl_xor(ps, 4);
        ps += __shfl_xor(ps, 8);
        lsum[qh][r] = lsum[qh][r] * sc + ps;
        O[qh][0][r] *= sc;
        O[qh][1][r] *= sc;
      }
#pragma unroll
      for (int sub = 0; sub < 4; ++sub)
#pragma unroll
        for (int r = 0; r < 4; ++r)
          Pw[w][kg * 4 + r][sub * 16 + ln] = __float2bfloat16(p[sub][r]);
      // same-wave LDS RAW: compiler inserts lgkmcnt wait; no barrier needed
#pragma unroll
      for (int kk = 0; kk < 2; ++kk) {
        short8b aP = *(const short8b*)&Pw[w][ln][kk * 32 + kg * 8];
        O[qh][0] = __builtin_amdgcn_mfma_f32_16x16x32_bf16(aP, bV[kk][0], O[qh][0], 0, 0, 0);
        O[qh][1] = __builtin_amdgcn_mfma_f32_16x16x32_bf16(aP, bV[kk][1], O[qh][1], 0, 0, 0);
      }
    }
  }

  float* pob = PO + (size_t)(split * 16 + bh) * 2048 * 32;
  float* pmb = PML + (size_t)(split * 16 + bh) * 2048 * 2;
#pragma unroll
  for (int qh = 0; qh < 2; ++qh)
#pragma unroll
    for (int r = 0; r < 4; ++r) {
      int q = q0 + qh * 16 + kg * 4 + r;
      pob[(size_t)q * 32 + ln]      = O[qh][0][r];
      pob[(size_t)q * 32 + 16 + ln] = O[qh][1][r];
      if (ln == 0) *(float2*)&pmb[q * 2] = make_float2(mrun[qh][r], lsum[qh][r]);
    }
}

// ---------------------------------------------------------------------------
// K2b: merge split-S partials -> Ab (4096 x 256 bf16, out-proj activation)
// ---------------------------------------------------------------------------
__global__ __launch_bounds__(256) void combine_splits(
    const float* __restrict__ PO, const float* __restrict__ PML,
    __hip_bfloat16* __restrict__ Ab) {
  int idx = blockIdx.x * 256 + threadIdx.x;      // 32768 = 16 bh * 2048 q
  int bh = idx >> 11, q = idx & 2047;
  int n = bh >> 3, h = bh & 7;
  float m_s[4], l_s[4];
#pragma unroll
  for (int s = 0; s < 4; ++s) {
    float2 ml = *(const float2*)&PML[((size_t)(s * 16 + bh) * 2048 + q) * 2];
    m_s[s] = ml.x; l_s[s] = ml.y;
  }
  float mstar = fmaxf(fmaxf(m_s[0], m_s[1]), fmaxf(m_s[2], m_s[3]));
  float wgt[4], L = 0.f;
#pragma unroll
  for (int s = 0; s < 4; ++s) { wgt[s] = __expf(m_s[s] - mstar); L += l_s[s] * wgt[s]; }
  float inv = 1.f / L;
  __hip_bfloat16* outp = Ab + ((size_t)q * 2 + n) * 256 + h * 32;
#pragma unroll
  for (int d0 = 0; d0 < 8; ++d0) {
    float4 acc = {0.f, 0.f, 0.f, 0.f};
#pragma unroll
    for (int s = 0; s < 4; ++s) {
      float4 v = *(const float4*)&PO[((size_t)(s * 16 + bh) * 2048 + q) * 32 + d0 * 4];
      acc.x += wgt[s] * v.x; acc.y += wgt[s] * v.y;
      acc.z += wgt[s] * v.z; acc.w += wgt[s] * v.w;
    }
    union { ushort4 u; __hip_bfloat16 hh[4]; } o;
    o.hh[0] = __float2bfloat16(acc.x * inv); o.hh[1] = __float2bfloat16(acc.y * inv);
    o.hh[2] = __float2bfloat16(acc.z * inv); o.hh[3] = __float2bfloat16(acc.w * inv);
    *(ushort4*)&outp[d0 * 4] = o.u;
  }
}

// ---------------------------------------------------------------------------
// K3: out projection. out(4096 x 256, f32) = Ab(4096 x 256) @ Wob^T + bias
// ---------------------------------------------------------------------------
__global__ __launch_bounds__(256) void out_gemm(
    const __hip_bfloat16* __restrict__ A, const __hip_bfloat16* __restrict__ W,
    const float* __restrict__ bias, float* __restrict__ out) {
    __shared__ __hip_bfloat16 At[128][40];
    __shared__ __hip_bfloat16 Bt[128][40];
    const int tid = threadIdx.x;
    const int lane = tid & 63, w = tid >> 6;
    const int ln = lane & 15, kg = lane >> 4;
    const int wr = w >> 1, wc = w & 1;
    const int rowBase = blockIdx.y * 128;
    const int colBase = blockIdx.x * 128;
    float4v acc[4][4] = {};

    for (int kt = 0; kt < 8; ++kt) {
        int cid = tid;
#pragma unroll
        for (int p = 0; p < 2; ++p, cid += 256) {
            int row = cid >> 2, c = cid & 3;
            *(short8b*)&At[row][c * 8] =
                *(const short8b*)&A[(rowBase + row) * 256 + kt * 32 + c * 8];
            *(short8b*)&Bt[row][c * 8] =
                *(const short8b*)&W[(colBase + row) * 256 + kt * 32 + c * 8];
        }
        __syncthreads();
        short8b a[4], b[4];
#pragma unroll
        for (int mi = 0; mi < 4; ++mi) a[mi] = *(const short8b*)&At[wr * 64 + mi * 16 + ln][kg * 8];
#pragma unroll
        for (int nj = 0; nj < 4; ++nj) b[nj] = *(const short8b*)&Bt[wc * 64 + nj * 16 + ln][kg * 8];
#pragma unroll
        for (int mi = 0; mi < 4; ++mi)
#pragma unroll
            for (int nj = 0; nj < 4; ++nj)
                acc[mi][nj] = __builtin_amdgcn_mfma_f32_16x16x32_bf16(a[mi], b[nj], acc[mi][nj], 0, 0, 0);
        __syncthreads();
    }

#pragma unroll
    for (int mi = 0; mi < 4; ++mi) {
#pragma unroll
        for (int nj = 0; nj < 4; ++nj) {
            int j = colBase + wc * 64 + nj * 16 + ln;
            float bj = bias[j];
#pragma unroll
            for (int r = 0; r < 4; ++r) {
                int row = rowBase + wr * 64 + mi * 16 + kg * 4 + r;
                out[row * 256 + j] = acc[mi][nj][r] + bj;
            }
        }
    }
}

// ---------------------------------------------------------------------------
extern "C" void kernel_launch(void* const* d_in, const int* in_sizes, int n_in,
                              void* d_out, int out_size, void* d_ws, size_t ws_size,
                              hipStream_t stream) {
    const float* query = (const float*)d_in[0];
    const float* W_in  = (const float*)d_in[1];
    const float* b_in  = (const float*)d_in[2];
    const float* W_s   = (const float*)d_in[3];
    const float* b_s   = (const float*)d_in[4];
    const float* W_o   = (const float*)d_in[5];
    const float* b_o   = (const float*)d_in[6];
    const int*   qids  = (const int*)d_in[7];
    const int*   kids  = (const int*)d_in[8];
    float* out = (float*)d_out;

    __hip_bfloat16* Xb  = (__hip_bfloat16*)d_ws;       // 4096 x 256
    __hip_bfloat16* Wb  = Xb + 4096 * 256;             // 1280 x 256
    __hip_bfloat16* Wob = Wb + 1280 * 256;             // 256 x 256
    __hip_bfloat16* Qs  = Wob + 256 * 256;             // [16][2048][32]
    __hip_bfloat16* Kg  = Qs + 16 * 2048 * 32;
    __hip_bfloat16* Vt  = Kg + 16 * 2048 * 32;         // [16][32][2048]
    __hip_bfloat16* Qf  = Vt + 16 * 2048 * 32;
    __hip_bfloat16* Kf  = Qf + 16 * 2048 * 32;
    __hip_bfloat16* Ab  = Kf + 16 * 2048 * 32;         // 4096 x 256
    float* PO  = (float*)(Ab + 4096 * 256);            // [4][16][2048][32] f32
    float* PML = PO + (size_t)4 * 16 * 2048 * 32;      // [4][16][2048][2] f32

    cast_all<<<1408, 256, 0, stream>>>(query, W_in, W_s, W_o, Xb, Wb, Wob);
    proj_gemm<<<dim3(10, 32), 256, 0, stream>>>(Xb, Wb, b_in, b_s, Qs, Kg, Vt, Qf, Kf);
    agent_attn<<<2048, 128, 0, stream>>>(Qs, Kg, Vt, Qf, Kf, qids, kids, PO, PML);
    combine_splits<<<128, 256, 0, stream>>>(PO, PML, Ab);
    out_gemm<<<dim3(2, 32), 256, 0, stream>>>(Ab, Wob, b_o, out);
}

// Round 3
// 81.117 us; speedup vs baseline: 1.3906x; 1.2669x over previous
//
#include <hip/hip_runtime.h>
#include <hip/hip_bf16.h>

typedef __attribute__((ext_vector_type(8))) short short8b;
typedef __attribute__((ext_vector_type(4))) float float4v;

static __device__ __forceinline__ unsigned short f2bf_bits(float f) {
  union { __hip_bfloat16 h; unsigned short u; } c;
  c.h = __float2bfloat16(f);
  return c.u;
}

// ---------------------------------------------------------------------------
// K0: fused f32 -> bf16 cast for query + all three weight matrices.
// ---------------------------------------------------------------------------
__global__ __launch_bounds__(256) void cast_all(
    const float* __restrict__ q, const float* __restrict__ w1,
    const float* __restrict__ w2, const float* __restrict__ w3,
    __hip_bfloat16* __restrict__ Xb, __hip_bfloat16* __restrict__ Wb,
    __hip_bfloat16* __restrict__ Wob) {
  int i = blockIdx.x * blockDim.x + threadIdx.x;
  if (i >= 360448) return;
  const float* src; __hip_bfloat16* dst; int j;
  if (i < 262144)      { src = q;  dst = Xb;          j = i; }
  else if (i < 311296) { src = w1; dst = Wb;          j = i - 262144; }
  else if (i < 344064) { src = w2; dst = Wb + 196608; j = i - 311296; }
  else                 { src = w3; dst = Wob;         j = i - 344064; }
  float4 v = reinterpret_cast<const float4*>(src)[j];
  union { ushort4 u; __hip_bfloat16 h[4]; } o;
  o.h[0] = __float2bfloat16(v.x); o.h[1] = __float2bfloat16(v.y);
  o.h[2] = __float2bfloat16(v.z); o.h[3] = __float2bfloat16(v.w);
  reinterpret_cast<ushort4*>(dst)[j] = o.u;
}

// ---------------------------------------------------------------------------
// K1: projection GEMM. C(4096 x 1280) = X(4096 x 256) @ W^T.
// Q-scaling now includes log2(e) so attention works in the exp2 domain.
// ---------------------------------------------------------------------------
__global__ __launch_bounds__(256) void proj_gemm(
    const __hip_bfloat16* __restrict__ X, const __hip_bfloat16* __restrict__ W,
    const float* __restrict__ bias, const float* __restrict__ bias_s,
    __hip_bfloat16* __restrict__ Qs, __hip_bfloat16* __restrict__ Kg,
    __hip_bfloat16* __restrict__ Vt, __hip_bfloat16* __restrict__ Qf,
    __hip_bfloat16* __restrict__ Kf) {
    __shared__ __hip_bfloat16 At[128][40];
    __shared__ __hip_bfloat16 Bt[128][40];
    const int tid = threadIdx.x;
    const int lane = tid & 63, w = tid >> 6;
    const int ln = lane & 15, kg = lane >> 4;
    const int wr = w >> 1, wc = w & 1;
    const int rowBase = blockIdx.y * 128;
    const int colBase = blockIdx.x * 128;
    float4v acc[4][4] = {};

    for (int kt = 0; kt < 8; ++kt) {
        int cid = tid;
#pragma unroll
        for (int p = 0; p < 2; ++p, cid += 256) {
            int row = cid >> 2, c = cid & 3;
            *(short8b*)&At[row][c * 8] =
                *(const short8b*)&X[(rowBase + row) * 256 + kt * 32 + c * 8];
            *(short8b*)&Bt[row][c * 8] =
                *(const short8b*)&W[(colBase + row) * 256 + kt * 32 + c * 8];
        }
        __syncthreads();
        short8b a[4], b[4];
#pragma unroll
        for (int mi = 0; mi < 4; ++mi) a[mi] = *(const short8b*)&At[wr * 64 + mi * 16 + ln][kg * 8];
#pragma unroll
        for (int nj = 0; nj < 4; ++nj) b[nj] = *(const short8b*)&Bt[wc * 64 + nj * 16 + ln][kg * 8];
#pragma unroll
        for (int mi = 0; mi < 4; ++mi)
#pragma unroll
            for (int nj = 0; nj < 4; ++nj)
                acc[mi][nj] = __builtin_amdgcn_mfma_f32_16x16x32_bf16(a[mi], b[nj], acc[mi][nj], 0, 0, 0);
        __syncthreads();
    }

    const float scaling = 0.17677669529663687f * 1.4426950408889634f;  // 32^-0.5 * log2(e)
#pragma unroll
    for (int mi = 0; mi < 4; ++mi) {
#pragma unroll
        for (int nj = 0; nj < 4; ++nj) {
            int j = colBase + wc * 64 + nj * 16 + ln;
            float bj = (j < 768) ? bias[j] : bias_s[j - 768];
#pragma unroll
            for (int r = 0; r < 4; ++r) {
                int row = rowBase + wr * 64 + mi * 16 + kg * 4 + r;
                float val = acc[mi][nj][r] + bj;
                int l = row >> 1, n = row & 1;
                if (j < 256) {
                    int h = j >> 5, d = j & 31;
                    Qs[(((n << 3) + h) * 2048 + l) * 32 + d] = __float2bfloat16(val * scaling);
                } else if (j < 512) {
                    int e = j - 256, h = e >> 5, d = e & 31;
                    Kg[(((n << 3) + h) * 2048 + l) * 32 + d] = __float2bfloat16(val);
                } else if (j < 768) {
                    int e = j - 512, h = e >> 5, d = e & 31;
                    Vt[(((n << 3) + h) * 32 + d) * 2048 + l] = __float2bfloat16(val);
                } else if (j < 1024) {
                    int e = j - 768, h = e >> 5, d = e & 31;
                    Qf[(((n << 3) + h) * 2048 + l) * 32 + d] = __float2bfloat16(val * scaling);
                } else {
                    int e = j - 1024, h = e >> 5, d = e & 31;
                    Kf[(((n << 3) + h) * 2048 + l) * 32 + d] = __float2bfloat16(val);
                }
            }
        }
    }
}

// ---------------------------------------------------------------------------
// K2: agent-aware flash attention, swapped-operand softmax + prefetch.
// grid: 2048 1-D blocks of 128 threads (2 independent waves, 32 q-rows each).
// Swapped QK: C = mfma(K_frag, Q_frag) -> C[s = kg*4+r (+16*sub)][q = ln]:
// each lane holds 16 s-values of ONE q-row -> softmax is in-lane tree +
// 2 shfl_xor. Defer-max (thr=8, log2 domain) skips O-rescale almost always.
// K/Ks/kid double-buffered in registers; V issued early each iteration.
// ---------------------------------------------------------------------------
__global__ __launch_bounds__(128) void agent_attn(
    const __hip_bfloat16* __restrict__ Qs, const __hip_bfloat16* __restrict__ Kg,
    const __hip_bfloat16* __restrict__ Vt, const __hip_bfloat16* __restrict__ Qf,
    const __hip_bfloat16* __restrict__ Kf, const int* __restrict__ qid_g,
    const int* __restrict__ kid_g, float* __restrict__ PO, float* __restrict__ PML) {
  __shared__ __align__(16) __hip_bfloat16 Pw[2][16][72];  // [wave][q][s], 144B rows
  const int tid = threadIdx.x;
  const int lane = tid & 63, w = tid >> 6;
  const int ln = lane & 15, kg = lane >> 4;

  const int flat = blockIdx.x;
  const int slot = flat >> 3;
  const int bh = ((flat & 7) << 1) | (slot & 1);
  const int qs = slot >> 1;
  const int qg = qs & 31, split = qs >> 5;
  const int q0 = qg * 64 + w * 32;

  const __hip_bfloat16* Qb  = Qs + (size_t)bh * 2048 * 32;
  const __hip_bfloat16* Qfb = Qf + (size_t)bh * 2048 * 32;
  const __hip_bfloat16* Kb  = Kg + (size_t)bh * 2048 * 32;
  const __hip_bfloat16* Ksb = Kf + (size_t)bh * 2048 * 32;
  const __hip_bfloat16* Vb  = Vt + (size_t)bh * 32 * 2048;

  // Q fragments (B-operand: row=q=ln, k=kg*8+j) + per-lane q identity
  short8b bQ[2], bQf[2];
  int qidq[2];
#pragma unroll
  for (int qh = 0; qh < 2; ++qh) {
    bQ[qh]  = *(const short8b*)&Qb [(q0 + qh * 16 + ln) * 32 + kg * 8];
    bQf[qh] = *(const short8b*)&Qfb[(q0 + qh * 16 + ln) * 32 + kg * 8];
    qidq[qh] = qid_g[q0 + qh * 16 + ln];
  }

  float m[2] = {-1e30f, -1e30f};   // running max (log2 domain), q = ln
  float l[2] = {0.f, 0.f};
  float4v O[2][2] = {};            // [qh][dh], layout C[q=kg*4+r][d=ln]

  short8b aK0[4], aS0[4], aK1[4], aS1[4];
  int sd0[4][4], sd1[4][4];

  auto LOADK = [&](int s0, short8b (&k)[4], short8b (&s)[4], int (&sd)[4][4]) {
#pragma unroll
    for (int sub = 0; sub < 4; ++sub) {
      k[sub] = *(const short8b*)&Kb [(s0 + sub * 16 + ln) * 32 + kg * 8];
      s[sub] = *(const short8b*)&Ksb[(s0 + sub * 16 + ln) * 32 + kg * 8];
      int4 t = *(const int4*)&kid_g[s0 + sub * 16 + kg * 4];
      sd[sub][0] = t.x; sd[sub][1] = t.y; sd[sub][2] = t.z; sd[sub][3] = t.w;
    }
  };

  auto TILE = [&](int s0, const short8b (&aK)[4], const short8b (&aS)[4],
                  const int (&sd)[4][4]) {
    // V early issue: used only after softmax (~400cy later)
    short8b bV[2][2];
#pragma unroll
    for (int kk = 0; kk < 2; ++kk)
#pragma unroll
      for (int dh = 0; dh < 2; ++dh)
        bV[kk][dh] = *(const short8b*)&Vb[(dh * 16 + ln) * 2048 + s0 + kk * 32 + kg * 8];

#pragma unroll
    for (int qh = 0; qh < 2; ++qh) {
      float4v ci[4], cs[4];
      float4v z = {0.f, 0.f, 0.f, 0.f};
#pragma unroll
      for (int sub = 0; sub < 4; ++sub) {
        ci[sub] = __builtin_amdgcn_mfma_f32_16x16x32_bf16(aK[sub], bQ[qh],  z, 0, 0, 0);
        cs[sub] = __builtin_amdgcn_mfma_f32_16x16x32_bf16(aS[sub], bQf[qh], z, 0, 0, 0);
      }
      // blend by agent identity; values for q=ln, s=s0+sub*16+kg*4+r
      float p[4][4];
      float tm = -1e30f;
#pragma unroll
      for (int sub = 0; sub < 4; ++sub)
#pragma unroll
        for (int r = 0; r < 4; ++r) {
          float v = (sd[sub][r] == qidq[qh]) ? cs[sub][r] : ci[sub][r];
          p[sub][r] = v;
          tm = fmaxf(tm, v);
        }
      tm = fmaxf(tm, __shfl_xor(tm, 16));
      tm = fmaxf(tm, __shfl_xor(tm, 32));
      if (__any(tm > m[qh] + 8.f)) {        // defer-max: rare after tile 0
        float mn = fmaxf(m[qh], tm);
        float scl = exp2f(m[qh] - mn);
        m[qh] = mn;
        l[qh] *= scl;
        float s0_ = __shfl(scl, kg * 4 + 0);
        float s1_ = __shfl(scl, kg * 4 + 1);
        float s2_ = __shfl(scl, kg * 4 + 2);
        float s3_ = __shfl(scl, kg * 4 + 3);
#pragma unroll
        for (int dh = 0; dh < 2; ++dh) {
          O[qh][dh][0] *= s0_; O[qh][dh][1] *= s1_;
          O[qh][dh][2] *= s2_; O[qh][dh][3] *= s3_;
        }
      }
      float ps = 0.f;
#pragma unroll
      for (int sub = 0; sub < 4; ++sub)
#pragma unroll
        for (int r = 0; r < 4; ++r) {
          float e = exp2f(p[sub][r] - m[qh]);
          p[sub][r] = e;
          ps += e;
        }
      ps += __shfl_xor(ps, 16);
      ps += __shfl_xor(ps, 32);
      l[qh] += ps;
      // P -> per-wave LDS [q=ln][s], b64 writes (bank-balanced)
#pragma unroll
      for (int sub = 0; sub < 4; ++sub) {
        ushort4 pk;
        pk.x = f2bf_bits(p[sub][0]); pk.y = f2bf_bits(p[sub][1]);
        pk.z = f2bf_bits(p[sub][2]); pk.w = f2bf_bits(p[sub][3]);
        *(ushort4*)&Pw[w][ln][sub * 16 + kg * 4] = pk;
      }
      // PV: A = P[q rows][s], B = V[d rows][s]  (same-wave LDS RAW, no barrier)
#pragma unroll
      for (int kk = 0; kk < 2; ++kk) {
        short8b aP = *(const short8b*)&Pw[w][ln][kk * 32 + kg * 8];
        O[qh][0] = __builtin_amdgcn_mfma_f32_16x16x32_bf16(aP, bV[kk][0], O[qh][0], 0, 0, 0);
        O[qh][1] = __builtin_amdgcn_mfma_f32_16x16x32_bf16(aP, bV[kk][1], O[qh][1], 0, 0, 0);
      }
    }
  };

  const int sbase = split * 512;
  LOADK(sbase, aK0, aS0, sd0);
#pragma unroll
  for (int st = 0; st < 8; st += 2) {
    LOADK(sbase + (st + 1) * 64, aK1, aS1, sd1);
    TILE(sbase + st * 64, aK0, aS0, sd0);
    if (st < 6) LOADK(sbase + (st + 2) * 64, aK0, aS0, sd0);
    TILE(sbase + (st + 1) * 64, aK1, aS1, sd1);
  }

  float* pob = PO + (size_t)(split * 16 + bh) * 2048 * 32;
  float* pmb = PML + (size_t)(split * 16 + bh) * 2048 * 2;
#pragma unroll
  for (int qh = 0; qh < 2; ++qh) {
#pragma unroll
    for (int r = 0; r < 4; ++r) {
      int q = q0 + qh * 16 + kg * 4 + r;
      pob[(size_t)q * 32 + ln]      = O[qh][0][r];
      pob[(size_t)q * 32 + 16 + ln] = O[qh][1][r];
    }
    if (kg == 0) {
      int q = q0 + qh * 16 + ln;
      *(float2*)&pmb[q * 2] = make_float2(m[qh], l[qh]);
    }
  }
}

// ---------------------------------------------------------------------------
// K2b: merge split-S partials -> Ab (4096 x 256 bf16). NOTE: log2 domain.
// ---------------------------------------------------------------------------
__global__ __launch_bounds__(128) void combine_splits(
    const float* __restrict__ PO, const float* __restrict__ PML,
    __hip_bfloat16* __restrict__ Ab) {
  int idx = blockIdx.x * 128 + threadIdx.x;      // 32768 = 16 bh * 2048 q
  int bh = idx >> 11, q = idx & 2047;
  int n = bh >> 3, h = bh & 7;
  float m_s[4], l_s[4];
#pragma unroll
  for (int s = 0; s < 4; ++s) {
    float2 ml = *(const float2*)&PML[((size_t)(s * 16 + bh) * 2048 + q) * 2];
    m_s[s] = ml.x; l_s[s] = ml.y;
  }
  float mstar = fmaxf(fmaxf(m_s[0], m_s[1]), fmaxf(m_s[2], m_s[3]));
  float wgt[4], L = 0.f;
#pragma unroll
  for (int s = 0; s < 4; ++s) { wgt[s] = exp2f(m_s[s] - mstar); L += l_s[s] * wgt[s]; }
  float inv = 1.f / L;
  __hip_bfloat16* outp = Ab + ((size_t)q * 2 + n) * 256 + h * 32;
#pragma unroll
  for (int d0 = 0; d0 < 8; ++d0) {
    float4 acc = {0.f, 0.f, 0.f, 0.f};
#pragma unroll
    for (int s = 0; s < 4; ++s) {
      float4 v = *(const float4*)&PO[((size_t)(s * 16 + bh) * 2048 + q) * 32 + d0 * 4];
      acc.x += wgt[s] * v.x; acc.y += wgt[s] * v.y;
      acc.z += wgt[s] * v.z; acc.w += wgt[s] * v.w;
    }
    union { ushort4 u; __hip_bfloat16 hh[4]; } o;
    o.hh[0] = __float2bfloat16(acc.x * inv); o.hh[1] = __float2bfloat16(acc.y * inv);
    o.hh[2] = __float2bfloat16(acc.z * inv); o.hh[3] = __float2bfloat16(acc.w * inv);
    *(ushort4*)&outp[d0 * 4] = o.u;
  }
}

// ---------------------------------------------------------------------------
// K3: out projection, 64x64 tiles (256 blocks). out = Ab @ Wob^T + bias (f32)
// ---------------------------------------------------------------------------
__global__ __launch_bounds__(256) void out_gemm(
    const __hip_bfloat16* __restrict__ A, const __hip_bfloat16* __restrict__ W,
    const float* __restrict__ bias, float* __restrict__ out) {
    __shared__ __hip_bfloat16 At[64][40];
    __shared__ __hip_bfloat16 Bt[64][40];
    const int tid = threadIdx.x;
    const int lane = tid & 63, w = tid >> 6;
    const int ln = lane & 15, kg = lane >> 4;
    const int wr = w >> 1, wc = w & 1;
    const int rowBase = blockIdx.y * 64;
    const int colBase = blockIdx.x * 64;
    float4v acc[2][2] = {};

    for (int kt = 0; kt < 8; ++kt) {
        int row = tid >> 2, c = tid & 3;
        *(short8b*)&At[row][c * 8] =
            *(const short8b*)&A[(rowBase + row) * 256 + kt * 32 + c * 8];
        *(short8b*)&Bt[row][c * 8] =
            *(const short8b*)&W[(colBase + row) * 256 + kt * 32 + c * 8];
        __syncthreads();
        short8b a[2], b[2];
#pragma unroll
        for (int mi = 0; mi < 2; ++mi) a[mi] = *(const short8b*)&At[wr * 32 + mi * 16 + ln][kg * 8];
#pragma unroll
        for (int nj = 0; nj < 2; ++nj) b[nj] = *(const short8b*)&Bt[wc * 32 + nj * 16 + ln][kg * 8];
#pragma unroll
        for (int mi = 0; mi < 2; ++mi)
#pragma unroll
            for (int nj = 0; nj < 2; ++nj)
                acc[mi][nj] = __builtin_amdgcn_mfma_f32_16x16x32_bf16(a[mi], b[nj], acc[mi][nj], 0, 0, 0);
        __syncthreads();
    }

#pragma unroll
    for (int mi = 0; mi < 2; ++mi) {
#pragma unroll
        for (int nj = 0; nj < 2; ++nj) {
            int j = colBase + wc * 32 + nj * 16 + ln;
            float bj = bias[j];
#pragma unroll
            for (int r = 0; r < 4; ++r) {
                int row = rowBase + wr * 32 + mi * 16 + kg * 4 + r;
                out[row * 256 + j] = acc[mi][nj][r] + bj;
            }
        }
    }
}

// ---------------------------------------------------------------------------
extern "C" void kernel_launch(void* const* d_in, const int* in_sizes, int n_in,
                              void* d_out, int out_size, void* d_ws, size_t ws_size,
                              hipStream_t stream) {
    const float* query = (const float*)d_in[0];
    const float* W_in  = (const float*)d_in[1];
    const float* b_in  = (const float*)d_in[2];
    const float* W_s   = (const float*)d_in[3];
    const float* b_s   = (const float*)d_in[4];
    const float* W_o   = (const float*)d_in[5];
    const float* b_o   = (const float*)d_in[6];
    const int*   qids  = (const int*)d_in[7];
    const int*   kids  = (const int*)d_in[8];
    float* out = (float*)d_out;

    __hip_bfloat16* Xb  = (__hip_bfloat16*)d_ws;       // 4096 x 256
    __hip_bfloat16* Wb  = Xb + 4096 * 256;             // 1280 x 256
    __hip_bfloat16* Wob = Wb + 1280 * 256;             // 256 x 256
    __hip_bfloat16* Qs  = Wob + 256 * 256;             // [16][2048][32]
    __hip_bfloat16* Kg  = Qs + 16 * 2048 * 32;
    __hip_bfloat16* Vt  = Kg + 16 * 2048 * 32;         // [16][32][2048]
    __hip_bfloat16* Qf  = Vt + 16 * 2048 * 32;
    __hip_bfloat16* Kf  = Qf + 16 * 2048 * 32;
    __hip_bfloat16* Ab  = Kf + 16 * 2048 * 32;         // 4096 x 256
    float* PO  = (float*)(Ab + 4096 * 256);            // [4][16][2048][32] f32
    float* PML = PO + (size_t)4 * 16 * 2048 * 32;      // [4][16][2048][2] f32

    cast_all<<<1408, 256, 0, stream>>>(query, W_in, W_s, W_o, Xb, Wb, Wob);
    proj_gemm<<<dim3(10, 32), 256, 0, stream>>>(Xb, Wb, b_in, b_s, Qs, Kg, Vt, Qf, Kf);
    agent_attn<<<2048, 128, 0, stream>>>(Qs, Kg, Vt, Qf, Kf, qids, kids, PO, PML);
    combine_splits<<<256, 128, 0, stream>>>(PO, PML, Ab);
    out_gemm<<<dim3(4, 64), 256, 0, stream>>>(Ab, Wob, b_o, out);
}